// Round 4
// baseline (248.637 us; speedup 1.0000x reference)
//
#include <hip/hip_runtime.h>
#include <hip/hip_bf16.h>
#include <math.h>

#define BB   16
#define NN   96
#define DD   128
#define NCLS 10

typedef __attribute__((ext_vector_type(8))) short bf16x8;
typedef __attribute__((ext_vector_type(4))) float f32x4;

__device__ __forceinline__ float scalar_as_float(int v) {
    if (v >= -1000000 && v <= 1000000) return (float)v;
    return __int_as_float(v);
}
__device__ __forceinline__ unsigned short f2bf(float f) {
    unsigned u = __float_as_uint(f);
    return (unsigned short)((u + 0x7FFFu + ((u >> 16) & 1u)) >> 16);
}
__device__ __forceinline__ float bf2f(unsigned short h) {
    return __uint_as_float(((unsigned)h) << 16);
}

// ---------------- one-time: pack W2 into MFMA B-fragments, bf16 hi + lo ----------------
// frag-major: [dtile 0..7][kchunk 0..3][lane 0..63][e 0..7]
// B-frag (16x16x32): lane l holds B[k = kc*32 + (l>>4)*8 + e][col = dt*16 + (l&15)]
__global__ __launch_bounds__(256) void k_w2prep(
    const float* __restrict__ W2, unsigned short* __restrict__ whi,
    unsigned short* __restrict__ wlo)
{
    const int dt = blockIdx.x;
    const int kc = threadIdx.x >> 6;
    const int l  = threadIdx.x & 63;
    const int base = ((dt * 4 + kc) * 64 + l) * 8;
    const int c = dt * 16 + (l & 15);
#pragma unroll
    for (int e = 0; e < 8; ++e) {
        const int k = kc * 32 + (l >> 4) * 8 + e;
        const float wv = W2[k * DD + c];
        const unsigned short h = f2bf(wv);
        whi[base + e] = h;
        wlo[base + e] = f2bf(wv - bf2f(h));
    }
}

// ---------------- one-time: AT[b][i][j] = A[b][j][i] ----------------
__global__ __launch_bounds__(256) void k_atrans(
    const float* __restrict__ A, float* __restrict__ AT)
{
    const int b = blockIdx.x;
    __shared__ float tile[NN][NN + 1];
    for (int idx = threadIdx.x; idx < NN * NN; idx += 256)
        tile[idx / NN][idx % NN] = A[b * NN * NN + idx];
    __syncthreads();
    for (int idx = threadIdx.x; idx < NN * NN; idx += 256) {
        const int i = idx / NN, j = idx % NN;
        AT[b * NN * NN + idx] = tile[j][i];
    }
}

// ---------------- init: x = e = embed_W[tok]; e_proj = e@W1e; xjA = e@W1x ----------------
__global__ __launch_bounds__(128) void k_init(
    const int* __restrict__ tok, const float* __restrict__ embed_W,
    const float* __restrict__ W1, float* __restrict__ x,
    float* __restrict__ e_proj, float* __restrict__ xj)
{
    const int row = blockIdx.y * NN + blockIdx.x;
    const int t = threadIdx.x;
    __shared__ float e_s[DD];
    const float ev = embed_W[tok[row] * DD + t];
    e_s[t] = ev;
    x[row * DD + t] = ev;
    __syncthreads();
    float a1 = 0.f, a2 = 0.f;
#pragma unroll 8
    for (int k = 0; k < DD; ++k) {
        const float e = e_s[k];
        a1 = fmaf(e, W1[k * DD + t], a1);
        a2 = fmaf(e, W1[(DD + k) * DD + t], a2);
    }
    e_proj[row * DD + t] = a1;
    xj[row * DD + t]     = a2;
}

#define MFMA(A, B, C) __builtin_amdgcn_mfma_f32_16x16x32_bf16(A, B, C, 0, 0, 0)

// ---------------- fully-fused per-round kernel: block=(b,i), 8 waves ----------------
// GEMM (MFMA, hi/lo W2) + A-agg + x-update + discretize + next-round xj (FIN=0)
// or final head -> out/x_all (FIN=1)
template<int FIN>
__global__ __launch_bounds__(512, 6) void k_round(
    const float* __restrict__ AT, const float* __restrict__ e_proj,
    const float* __restrict__ xj_in, const float* __restrict__ b1,
    const unsigned short* __restrict__ w2hi, const unsigned short* __restrict__ w2lo,
    const float* __restrict__ b2,
    const float* __restrict__ Wo1, const float* __restrict__ bo1,
    const float* __restrict__ Wo2, const float* __restrict__ embed_W,
    const float* __restrict__ W1x, const int* __restrict__ tau_p,
    float* __restrict__ x, float* __restrict__ xj_out,
    float* __restrict__ out, float* __restrict__ x_all)
{
    const int i = blockIdx.x;
    const int b = blockIdx.y;
    const int t = threadIdx.x;   // 0..511
    const int w = t >> 6;        // wave = d-tile 0..7
    const int l = t & 63;
    const int row = b * NN + i;

    __shared__ __align__(16) unsigned short hs[NN * DD];  // XOR-swizzled bf16 H
    __shared__ float v_s[DD];
    __shared__ float ac_s[NN];
    __shared__ float agg_s[DD];
    __shared__ float xn_s[DD];
    __shared__ float part_s[4][DD];
    __shared__ float wred[2][NCLS];

    // early-issue the xj tile loads (fly during barrier/frag loads)
    const float4* src = (const float4*)(xj_in + b * NN * DD);
    float4 u[6];
#pragma unroll
    for (int it = 0; it < 6; ++it) u[it] = src[t + it * 512];

    if (t < DD) v_s[t] = e_proj[row * DD + t] + b1[t];
    else if (t < DD + NN) ac_s[t - DD] = AT[row * NN + (t - DD)];

    // B-fragments for this wave's d-tile: hi + lo, frag-major from L2
    const bf16x8* WH = (const bf16x8*)w2hi;
    const bf16x8* WL = (const bf16x8*)w2lo;
    bf16x8 bh[4], bl[4];
#pragma unroll
    for (int kc = 0; kc < 4; ++kc) {
        bh[kc] = WH[(w * 4 + kc) * 64 + l];
        bl[kc] = WL[(w * 4 + kc) * 64 + l];
    }
    const float b2v = b2[w * 16 + (l & 15)];
    __syncthreads();

    {   // H = relu(v + xj) -> bf16 LDS, swizzled: short_idx ^ ((row&7)<<3)
        const float4* vv = (const float4*)v_s;
#pragma unroll
        for (int it = 0; it < 6; ++it) {
            const int idx = t + it * 512;          // 0..3071
            const int j = idx >> 5, k4 = (idx & 31) << 2;
            const float4 v = vv[idx & 31];
            ushort4 hh;
            hh.x = f2bf(fmaxf(u[it].x + v.x, 0.f));
            hh.y = f2bf(fmaxf(u[it].y + v.y, 0.f));
            hh.z = f2bf(fmaxf(u[it].z + v.z, 0.f));
            hh.w = f2bf(fmaxf(u[it].w + v.w, 0.f));
            *(ushort4*)&hs[(j * DD + k4) ^ ((j & 7) << 3)] = hh;
        }
    }
    __syncthreads();

    // GEMM: wave sweeps six 16-row j-tiles for its one 16-col d-tile (hi+lo MFMA)
    float aggp = 0.f;
#pragma unroll
    for (int jt = 0; jt < 6; ++jt) {
        const int r16 = jt * 16 + (l & 15);
        const int ko  = (l >> 4) * 8;
        const int sw  = (r16 & 7) << 3;
        const bf16x8 a0 = *(const bf16x8*)&hs[(r16 * DD + ko     ) ^ sw];
        const bf16x8 a1 = *(const bf16x8*)&hs[(r16 * DD + ko + 32) ^ sw];
        const bf16x8 a2 = *(const bf16x8*)&hs[(r16 * DD + ko + 64) ^ sw];
        const bf16x8 a3 = *(const bf16x8*)&hs[(r16 * DD + ko + 96) ^ sw];
        f32x4 ch = {0.f, 0.f, 0.f, 0.f}, cl = {0.f, 0.f, 0.f, 0.f};
        ch = MFMA(a0, bh[0], ch);  cl = MFMA(a0, bl[0], cl);
        ch = MFMA(a1, bh[1], ch);  cl = MFMA(a1, bl[1], cl);
        ch = MFMA(a2, bh[2], ch);  cl = MFMA(a2, bl[2], cl);
        ch = MFMA(a3, bh[3], ch);  cl = MFMA(a3, bl[3], cl);
        const f32x4 m = ch + cl;
#pragma unroll
        for (int r = 0; r < 4; ++r) {
            const float a = ac_s[jt * 16 + (l >> 4) * 4 + r];
            aggp = fmaf(a, fmaxf(m[r] + b2v, 0.f), aggp);
        }
    }
    aggp += __shfl_xor(aggp, 16);
    aggp += __shfl_xor(aggp, 32);
    if (l < 16) agg_s[w * 16 + l] = aggp;
    __syncthreads();

    // ---- epilogue: x-update + head(+discretize+xj) fused, block-local ----
    float xn = 0.f;
    if (t < DD) {
        xn = x[row * DD + t] + agg_s[t];
        xn_s[t] = xn;
    }
    __syncthreads();

    {   // hid partials: quarter q sums 32 k's for output h
        const int q = t >> 7, h = t & 127;
        float pp = 0.f;
#pragma unroll
        for (int kk = 0; kk < 32; ++kk) {
            const int k = q * 32 + kk;
            pp = fmaf(xn_s[k], Wo1[k * DD + h], pp);
        }
        part_s[q][h] = pp;
    }
    __syncthreads();

    if (t < DD) {   // waves 0,1 fully active: butterfly is safe
        const float hid = fmaxf(part_s[0][t] + part_s[1][t] + part_s[2][t] + part_s[3][t]
                                + bo1[t], 0.f);
        float lgp[NCLS];
#pragma unroll
        for (int c = 0; c < NCLS; ++c) lgp[c] = hid * Wo2[t * NCLS + c];
#pragma unroll
        for (int s = 1; s < 64; s <<= 1) {
#pragma unroll
            for (int c = 0; c < NCLS; ++c) lgp[c] += __shfl_xor(lgp[c], s);
        }
        if (l == 0) {
#pragma unroll
            for (int c = 0; c < NCLS; ++c) wred[w][c] = lgp[c];
        }
    }
    __syncthreads();

    if (FIN) {
        if (t < NCLS) {
            const float lg = wred[0][t] + wred[1][t];
            x_all[row * NCLS + t] = lg;
            if (i == 0) out[b * NCLS + t] = lg;
        }
        return;
    }

    // discretize: redundant per-thread softmax, then x += p @ centroids
    if (t < DD) {
        float lg[NCLS];
        float mx = -1e30f;
#pragma unroll
        for (int c = 0; c < NCLS; ++c) {
            lg[c] = wred[0][c] + wred[1][c];
            mx = fmaxf(mx, lg[c]);
        }
        const float inv_tau = 1.f / scalar_as_float(tau_p[0]);
        float p[NCLS], den = 0.f;
#pragma unroll
        for (int c = 0; c < NCLS; ++c) { p[c] = expf((lg[c] - mx) * inv_tau); den += p[c]; }
        const float invden = 1.f / den;
#pragma unroll
        for (int c = 0; c < NCLS; ++c)
            xn = fmaf(p[c] * invden, embed_W[(4 + c) * DD + t], xn);
        x[row * DD + t] = xn;
        xn_s[t] = xn;
    }
    __syncthreads();

    {   // next round's xj = xn @ W1x
        const int q = t >> 7, h = t & 127;
        float pp = 0.f;
#pragma unroll
        for (int kk = 0; kk < 32; ++kk) {
            const int k = q * 32 + kk;
            pp = fmaf(xn_s[k], W1x[k * DD + h], pp);
        }
        part_s[q][h] = pp;
    }
    __syncthreads();
    if (t < DD)
        xj_out[row * DD + t] = part_s[0][t] + part_s[1][t] + part_s[2][t] + part_s[3][t];
}

extern "C" void kernel_launch(void* const* d_in, const int* in_sizes, int n_in,
                              void* d_out, int out_size, void* d_ws, size_t ws_size,
                              hipStream_t stream)
{
    (void)in_sizes; (void)n_in; (void)out_size; (void)ws_size;
    const int*   tok     = (const int*)d_in[0];
    const float* Aab     = (const float*)d_in[1];
    const float* embed_W = (const float*)d_in[2];
    const float* W1      = (const float*)d_in[3];
    const float* b1      = (const float*)d_in[4];
    const float* W2      = (const float*)d_in[5];
    const float* b2      = (const float*)d_in[6];
    const float* Wo1     = (const float*)d_in[7];
    const float* bo1     = (const float*)d_in[8];
    const float* Wo2     = (const float*)d_in[9];
    const int*   tau_p   = (const int*)d_in[11];

    float* out   = (float*)d_out;
    float* x_all = out + BB * NCLS;

    float* ws     = (float*)d_ws;
    float* x      = ws;                                   // 196608 f
    float* e_proj = ws + BB * NN * DD;                    // 196608 f
    float* xjA    = ws + 2 * BB * NN * DD;                // 196608 f
    float* xjB    = ws + 3 * BB * NN * DD;                // 196608 f
    float* ATr    = ws + 4 * BB * NN * DD;                // 147456 f
    unsigned short* w2hi = (unsigned short*)(ws + 4 * BB * NN * DD + BB * NN * NN);
    unsigned short* w2lo = w2hi + DD * DD;

    const float* W1x = W1 + DD * DD;

    dim3 grid(NN, BB);
    k_w2prep<<<8, 256, 0, stream>>>(W2, w2hi, w2lo);
    k_atrans<<<BB, 256, 0, stream>>>(Aab, ATr);
    k_init<<<grid, 128, 0, stream>>>(tok, embed_W, W1, x, e_proj, xjA);
    for (int r = 0; r < 5; ++r) {
        const float* xin = (r & 1) ? xjB : xjA;
        float*       xot = (r & 1) ? xjA : xjB;
        if (r < 4)
            k_round<0><<<grid, 512, 0, stream>>>(ATr, e_proj, xin, b1, w2hi, w2lo, b2,
                                                 Wo1, bo1, Wo2, embed_W, W1x, tau_p,
                                                 x, xot, out, x_all);
        else
            k_round<1><<<grid, 512, 0, stream>>>(ATr, e_proj, xin, b1, w2hi, w2lo, b2,
                                                 Wo1, bo1, Wo2, embed_W, W1x, tau_p,
                                                 x, xot, out, x_all);
    }
}

// Round 5
// 138.208 us; speedup vs baseline: 1.7990x; 1.7990x over previous
//
#include <hip/hip_runtime.h>
#include <hip/hip_bf16.h>
#include <math.h>

#define BB   16
#define NN   96
#define DD   128
#define NCLS 10

typedef __attribute__((ext_vector_type(8))) short bf16x8;
typedef __attribute__((ext_vector_type(4))) float f32x4;

__device__ __forceinline__ float scalar_as_float(int v) {
    if (v >= -1000000 && v <= 1000000) return (float)v;
    return __int_as_float(v);
}
__device__ __forceinline__ unsigned short f2bf(float f) {
    unsigned u = __float_as_uint(f);
    return (unsigned short)((u + 0x7FFFu + ((u >> 16) & 1u)) >> 16);
}
__device__ __forceinline__ float bf2f(unsigned short h) {
    return __uint_as_float(((unsigned)h) << 16);
}

// ---------------- one-time: pack W2 into MFMA B-fragments, bf16 hi + lo ----------------
// frag-major: [dtile 0..7][kchunk 0..3][lane 0..63][e 0..7]
// B-frag (16x16x32): lane l holds B[k = kc*32 + (l>>4)*8 + e][col = dt*16 + (l&15)]
__global__ __launch_bounds__(256) void k_w2prep(
    const float* __restrict__ W2, unsigned short* __restrict__ whi,
    unsigned short* __restrict__ wlo)
{
    const int dt = blockIdx.x;
    const int kc = threadIdx.x >> 6;
    const int l  = threadIdx.x & 63;
    const int base = ((dt * 4 + kc) * 64 + l) * 8;
    const int c = dt * 16 + (l & 15);
#pragma unroll
    for (int e = 0; e < 8; ++e) {
        const int k = kc * 32 + (l >> 4) * 8 + e;
        const float wv = W2[k * DD + c];
        const unsigned short h = f2bf(wv);
        whi[base + e] = h;
        wlo[base + e] = f2bf(wv - bf2f(h));
    }
}

// ---------------- one-time: AT[b][i][j] = A[b][j][i] ----------------
__global__ __launch_bounds__(256) void k_atrans(
    const float* __restrict__ A, float* __restrict__ AT)
{
    const int b = blockIdx.x;
    __shared__ float tile[NN][NN + 1];
    for (int idx = threadIdx.x; idx < NN * NN; idx += 256)
        tile[idx / NN][idx % NN] = A[b * NN * NN + idx];
    __syncthreads();
    for (int idx = threadIdx.x; idx < NN * NN; idx += 256) {
        const int i = idx / NN, j = idx % NN;
        AT[b * NN * NN + idx] = tile[j][i];
    }
}

// ---------------- init: x = e = embed_W[tok]; e_proj = e@W1e; xjA = e@W1x ----------------
__global__ __launch_bounds__(128) void k_init(
    const int* __restrict__ tok, const float* __restrict__ embed_W,
    const float* __restrict__ W1, float* __restrict__ x,
    float* __restrict__ e_proj, float* __restrict__ xj)
{
    const int row = blockIdx.y * NN + blockIdx.x;
    const int t = threadIdx.x;
    __shared__ float e_s[DD];
    const float ev = embed_W[tok[row] * DD + t];
    e_s[t] = ev;
    x[row * DD + t] = ev;
    __syncthreads();
    float a1 = 0.f, a2 = 0.f;
#pragma unroll 8
    for (int k = 0; k < DD; ++k) {
        const float e = e_s[k];
        a1 = fmaf(e, W1[k * DD + t], a1);
        a2 = fmaf(e, W1[(DD + k) * DD + t], a2);
    }
    e_proj[row * DD + t] = a1;
    xj[row * DD + t]     = a2;
}

#define MFMA(A, B, C) __builtin_amdgcn_mfma_f32_16x16x32_bf16(A, B, C, 0, 0, 0)

// ---------------- fully-fused per-round kernel: block=(b,i), 8 waves ----------------
// GEMM (MFMA, hi/lo W2) + A-agg + x-update + discretize + next-round xj (FIN=0)
// or final head -> out/x_all (FIN=1)
// launch_bounds(512,4): 128-VGPR budget — R4's (512,6)/85-VGPR forced spills
// (52MB FETCH + 110MB WRITE scratch traffic per dispatch). 2 blocks/CU is enough.
template<int FIN>
__global__ __launch_bounds__(512, 4) void k_round(
    const float* __restrict__ AT, const float* __restrict__ e_proj,
    const float* __restrict__ xj_in, const float* __restrict__ b1,
    const unsigned short* __restrict__ w2hi, const unsigned short* __restrict__ w2lo,
    const float* __restrict__ b2,
    const float* __restrict__ Wo1, const float* __restrict__ bo1,
    const float* __restrict__ Wo2, const float* __restrict__ embed_W,
    const float* __restrict__ W1x, const int* __restrict__ tau_p,
    float* __restrict__ x, float* __restrict__ xj_out,
    float* __restrict__ out, float* __restrict__ x_all)
{
    const int i = blockIdx.x;
    const int b = blockIdx.y;
    const int t = threadIdx.x;   // 0..511
    const int w = t >> 6;        // wave = d-tile 0..7
    const int l = t & 63;
    const int row = b * NN + i;

    __shared__ __align__(16) unsigned short hs[NN * DD];  // XOR-swizzled bf16 H
    __shared__ float v_s[DD];
    __shared__ float ac_s[NN];
    __shared__ float agg_s[DD];
    __shared__ float xn_s[DD];
    __shared__ float part_s[4][DD];
    __shared__ float wred[2][NCLS];

    if (t < DD) v_s[t] = e_proj[row * DD + t] + b1[t];
    else if (t < DD + NN) ac_s[t - DD] = AT[row * NN + (t - DD)];

    // B-fragments for this wave's d-tile: hi + lo, frag-major from L2
    const bf16x8* WH = (const bf16x8*)w2hi;
    const bf16x8* WL = (const bf16x8*)w2lo;
    bf16x8 bh[4], bl[4];
#pragma unroll
    for (int kc = 0; kc < 4; ++kc) {
        bh[kc] = WH[(w * 4 + kc) * 64 + l];
        bl[kc] = WL[(w * 4 + kc) * 64 + l];
    }
    const float b2v = b2[w * 16 + (l & 15)];
    __syncthreads();

    {   // H = relu(v + xj) -> bf16 LDS, swizzled: short_idx ^ ((row&7)<<3)
        const float4* src = (const float4*)(xj_in + b * NN * DD);
        const float4* vv  = (const float4*)v_s;
#pragma unroll
        for (int it = 0; it < 6; ++it) {
            const int idx = t + it * 512;          // 0..3071
            const int j = idx >> 5, k4 = (idx & 31) << 2;
            const float4 u = src[idx];
            const float4 v = vv[idx & 31];
            ushort4 hh;
            hh.x = f2bf(fmaxf(u.x + v.x, 0.f));
            hh.y = f2bf(fmaxf(u.y + v.y, 0.f));
            hh.z = f2bf(fmaxf(u.z + v.z, 0.f));
            hh.w = f2bf(fmaxf(u.w + v.w, 0.f));
            *(ushort4*)&hs[(j * DD + k4) ^ ((j & 7) << 3)] = hh;
        }
    }
    __syncthreads();

    // GEMM: wave sweeps six 16-row j-tiles for its one 16-col d-tile (hi+lo MFMA)
    float aggp = 0.f;
#pragma unroll
    for (int jt = 0; jt < 6; ++jt) {
        const int r16 = jt * 16 + (l & 15);
        const int ko  = (l >> 4) * 8;
        const int sw  = (r16 & 7) << 3;
        const bf16x8 a0 = *(const bf16x8*)&hs[(r16 * DD + ko     ) ^ sw];
        const bf16x8 a1 = *(const bf16x8*)&hs[(r16 * DD + ko + 32) ^ sw];
        const bf16x8 a2 = *(const bf16x8*)&hs[(r16 * DD + ko + 64) ^ sw];
        const bf16x8 a3 = *(const bf16x8*)&hs[(r16 * DD + ko + 96) ^ sw];
        f32x4 ch = {0.f, 0.f, 0.f, 0.f}, cl = {0.f, 0.f, 0.f, 0.f};
        ch = MFMA(a0, bh[0], ch);  cl = MFMA(a0, bl[0], cl);
        ch = MFMA(a1, bh[1], ch);  cl = MFMA(a1, bl[1], cl);
        ch = MFMA(a2, bh[2], ch);  cl = MFMA(a2, bl[2], cl);
        ch = MFMA(a3, bh[3], ch);  cl = MFMA(a3, bl[3], cl);
        const f32x4 m = ch + cl;
#pragma unroll
        for (int r = 0; r < 4; ++r) {
            const float a = ac_s[jt * 16 + (l >> 4) * 4 + r];
            aggp = fmaf(a, fmaxf(m[r] + b2v, 0.f), aggp);
        }
    }
    aggp += __shfl_xor(aggp, 16);
    aggp += __shfl_xor(aggp, 32);
    if (l < 16) agg_s[w * 16 + l] = aggp;
    __syncthreads();

    // ---- epilogue: x-update + head(+discretize+xj) fused, block-local ----
    float xn = 0.f;
    if (t < DD) {
        xn = x[row * DD + t] + agg_s[t];
        xn_s[t] = xn;
    }
    __syncthreads();

    {   // hid partials: quarter q sums 32 k's for output h
        const int q = t >> 7, h = t & 127;
        float pp = 0.f;
#pragma unroll
        for (int kk = 0; kk < 32; ++kk) {
            const int k = q * 32 + kk;
            pp = fmaf(xn_s[k], Wo1[k * DD + h], pp);
        }
        part_s[q][h] = pp;
    }
    __syncthreads();

    if (t < DD) {   // waves 0,1 fully active: butterfly is safe
        const float hid = fmaxf(part_s[0][t] + part_s[1][t] + part_s[2][t] + part_s[3][t]
                                + bo1[t], 0.f);
        float lgp[NCLS];
#pragma unroll
        for (int c = 0; c < NCLS; ++c) lgp[c] = hid * Wo2[t * NCLS + c];
#pragma unroll
        for (int s = 1; s < 64; s <<= 1) {
#pragma unroll
            for (int c = 0; c < NCLS; ++c) lgp[c] += __shfl_xor(lgp[c], s);
        }
        if (l == 0) {
#pragma unroll
            for (int c = 0; c < NCLS; ++c) wred[w][c] = lgp[c];
        }
    }
    __syncthreads();

    if (FIN) {
        if (t < NCLS) {
            const float lg = wred[0][t] + wred[1][t];
            x_all[row * NCLS + t] = lg;
            if (i == 0) out[b * NCLS + t] = lg;
        }
        return;
    }

    // discretize: redundant per-thread softmax, then x += p @ centroids
    if (t < DD) {
        float lg[NCLS];
        float mx = -1e30f;
#pragma unroll
        for (int c = 0; c < NCLS; ++c) {
            lg[c] = wred[0][c] + wred[1][c];
            mx = fmaxf(mx, lg[c]);
        }
        const float inv_tau = 1.f / scalar_as_float(tau_p[0]);
        float p[NCLS], den = 0.f;
#pragma unroll
        for (int c = 0; c < NCLS; ++c) { p[c] = expf((lg[c] - mx) * inv_tau); den += p[c]; }
        const float invden = 1.f / den;
#pragma unroll
        for (int c = 0; c < NCLS; ++c)
            xn = fmaf(p[c] * invden, embed_W[(4 + c) * DD + t], xn);
        x[row * DD + t] = xn;
        xn_s[t] = xn;
    }
    __syncthreads();

    {   // next round's xj = xn @ W1x
        const int q = t >> 7, h = t & 127;
        float pp = 0.f;
#pragma unroll
        for (int kk = 0; kk < 32; ++kk) {
            const int k = q * 32 + kk;
            pp = fmaf(xn_s[k], W1x[k * DD + h], pp);
        }
        part_s[q][h] = pp;
    }
    __syncthreads();
    if (t < DD)
        xj_out[row * DD + t] = part_s[0][t] + part_s[1][t] + part_s[2][t] + part_s[3][t];
}

extern "C" void kernel_launch(void* const* d_in, const int* in_sizes, int n_in,
                              void* d_out, int out_size, void* d_ws, size_t ws_size,
                              hipStream_t stream)
{
    (void)in_sizes; (void)n_in; (void)out_size; (void)ws_size;
    const int*   tok     = (const int*)d_in[0];
    const float* Aab     = (const float*)d_in[1];
    const float* embed_W = (const float*)d_in[2];
    const float* W1      = (const float*)d_in[3];
    const float* b1      = (const float*)d_in[4];
    const float* W2      = (const float*)d_in[5];
    const float* b2      = (const float*)d_in[6];
    const float* Wo1     = (const float*)d_in[7];
    const float* bo1     = (const float*)d_in[8];
    const float* Wo2     = (const float*)d_in[9];
    const int*   tau_p   = (const int*)d_in[11];

    float* out   = (float*)d_out;
    float* x_all = out + BB * NCLS;

    float* ws     = (float*)d_ws;
    float* x      = ws;                                   // 196608 f
    float* e_proj = ws + BB * NN * DD;                    // 196608 f
    float* xjA    = ws + 2 * BB * NN * DD;                // 196608 f
    float* xjB    = ws + 3 * BB * NN * DD;                // 196608 f
    float* ATr    = ws + 4 * BB * NN * DD;                // 147456 f
    unsigned short* w2hi = (unsigned short*)(ws + 4 * BB * NN * DD + BB * NN * NN);
    unsigned short* w2lo = w2hi + DD * DD;

    const float* W1x = W1 + DD * DD;

    dim3 grid(NN, BB);
    k_w2prep<<<8, 256, 0, stream>>>(W2, w2hi, w2lo);
    k_atrans<<<BB, 256, 0, stream>>>(Aab, ATr);
    k_init<<<grid, 128, 0, stream>>>(tok, embed_W, W1, x, e_proj, xjA);
    for (int r = 0; r < 5; ++r) {
        const float* xin = (r & 1) ? xjB : xjA;
        float*       xot = (r & 1) ? xjA : xjB;
        if (r < 4)
            k_round<0><<<grid, 512, 0, stream>>>(ATr, e_proj, xin, b1, w2hi, w2lo, b2,
                                                 Wo1, bo1, Wo2, embed_W, W1x, tau_p,
                                                 x, xot, out, x_all);
        else
            k_round<1><<<grid, 512, 0, stream>>>(ATr, e_proj, xin, b1, w2hi, w2lo, b2,
                                                 Wo1, bo1, Wo2, embed_W, W1x, tau_p,
                                                 x, xot, out, x_all);
    }
}